// Round 1
// baseline (218.330 us; speedup 1.0000x reference)
//
#include <hip/hip_runtime.h>

// Word2VecEmbedding: gather table[ids] with ~5% UNK tokens replaced by the
// masked mean of the +-2 context window.
//   VOCAB=50000, DIM=300, PAD=0, UNK=1, CTX_W=2, B=32, S=4096
// d_in[0] = input_ids (B*S int32), d_in[1] = table (VOCAB*DIM f32)
// d_out   = (B,S,DIM) f32
//
// R3: exact-tiling (no bounds checks), ITEMS=8 for deeper MLP, branch-free
// parallel UNK repair (PAD row is guaranteed all-zero, so invalid neighbors
// are redirected to row 0 and accumulated unconditionally -> 4 independent
// gathers instead of a serialized conditional chain), and non-UNK stores
// issued BEFORE the repair phase so 95% of write traffic never waits on it.

#define PAD_ID 0
#define UNK_ID 1
#define SEQ    4096
#define DIM4   75     // 300 floats = 75 float4
#define TPB    256

typedef float vf4 __attribute__((ext_vector_type(4)));

template <int ITEMS, bool GUARD>
__global__ __launch_bounds__(TPB) void w2v_embed_kernel(
    const int* __restrict__ ids,
    const vf4* __restrict__ table4,
    vf4* __restrict__ out4,
    int total4)
{
    const int tid  = threadIdx.x;
    const int base = blockIdx.x * (TPB * ITEMS) + tid;

    int ii[ITEMS], tt[ITEMS], dd[ITEMS], idv[ITEMS];

    // Phase 1: index math + ITEMS independent ids loads.
#pragma unroll
    for (int u = 0; u < ITEMS; ++u) {
        int i = base + u * TPB;
        ii[u] = i;
        int t = (int)((unsigned)i / DIM4);          // magic-mul div
        tt[u] = t;
        dd[u] = i - t * DIM4;
        // GUARD OOB lanes read row PAD (0) which is always in range.
        idv[u] = (!GUARD || i < total4) ? ids[t] : PAD_ID;
    }

    // Phase 2: ITEMS independent center-row gathers (UNK row is a real table
    // row; loading it for UNK lanes keeps all loads unconditional).
    vf4 val[ITEMS];
#pragma unroll
    for (int u = 0; u < ITEMS; ++u) {
        val[u] = table4[idv[u] * DIM4 + dd[u]];
    }

    // Phase 3: stream out the ~95% non-UNK results immediately — their
    // stores must not wait on the repair path.
#pragma unroll
    for (int u = 0; u < ITEMS; ++u) {
        if ((!GUARD || ii[u] < total4) && idv[u] != UNK_ID)
            __builtin_nontemporal_store(val[u], &out4[ii[u]]);
    }

    // Phase 4: rare UNK repair (~5% of tokens). Branch-free: invalid
    // neighbors (seq-edge OOB, PAD, UNK) are redirected to table row
    // PAD_ID=0, which is all-zero by construction, so all 4 neighbor
    // gathers issue unconditionally and independently.
#pragma unroll
    for (int u = 0; u < ITEMS; ++u) {
        if (idv[u] == UNK_ID) {                     // GUARD-OOB lanes are PAD
            const int t = tt[u], d = dd[u];
            const int s = t & (SEQ - 1);

            int idn[4];
            const int off0[4] = {-2, -1, 1, 2};
#pragma unroll
            for (int j = 0; j < 4; ++j) {
                int sn = s + off0[j];
                bool in = (sn >= 0) && (sn < SEQ);  // zero-pad at seq edges
                int x = ids[in ? (t + off0[j]) : t];
                idn[j] = (in && x != UNK_ID) ? x : PAD_ID;
            }

            vf4 row[4];
#pragma unroll
            for (int j = 0; j < 4; ++j)             // 4 independent gathers
                row[j] = table4[idn[j] * DIM4 + d];

            float cnt = 0.f;
            vf4 acc = (vf4)0.f;
#pragma unroll
            for (int j = 0; j < 4; ++j) {
                acc += row[j];                      // row 0 contributes zeros
                cnt += (idn[j] != PAD_ID) ? 1.f : 0.f;
            }
            vf4 r = acc * (1.f / (cnt + 1e-8f));    // cnt==0 -> zeros
            __builtin_nontemporal_store(r, &out4[ii[u]]);
        }
    }
}

extern "C" void kernel_launch(void* const* d_in, const int* in_sizes, int n_in,
                              void* d_out, int out_size, void* d_ws, size_t ws_size,
                              hipStream_t stream)
{
    const int* ids    = (const int*)d_in[0];
    const vf4* table4 = (const vf4*)d_in[1];
    vf4*       out4   = (vf4*)d_out;

    int total4 = out_size / 4;                     // 9,830,400 (as in R2)
    constexpr int ITEMS = 8;
    const int per_block = TPB * ITEMS;             // 2048

    if (total4 % per_block == 0) {
        // exact tiling: 9,830,400 / 2048 = 4800 blocks, no bounds checks
        w2v_embed_kernel<ITEMS, false>
            <<<total4 / per_block, TPB, 0, stream>>>(ids, table4, out4, total4);
    } else {
        int grid = (total4 + per_block - 1) / per_block;
        w2v_embed_kernel<ITEMS, true>
            <<<grid, TPB, 0, stream>>>(ids, table4, out4, total4);
    }
}